// Round 5
// baseline (258.235 us; speedup 1.0000x reference)
//
#include <hip/hip_runtime.h>

// LSTM: B=16384 independent sequences, T=512, I=4, H=4, then FC 4->1.
// Round 7: CLEAN occupancy retest. R3's "2 waves don't overlap" conclusion
// was confounded: its gate exchange used ds_swizzle (LDS, ~120+cy latency +
// lgkmcnt waits) ON the recurrence cycle, so 700 cyc/step is consistent
// with either no-overlap of a 700cy chain or full overlap of a 1400cy
// chain. This round re-runs the 8-lane/seq split with a ZERO-LDS exchange:
// pair-selector at lane bit 3, exchange via DPP row_ror:8 (full-rate VALU
// lane permute, lane L <-> L^8 within a 16-lane row). h-broadcast stays
// 3 quad-perm DPPs (4 h-lanes of a seq are an aligned quad in each half).
// Per-wave issue ~halves (each lane computes one gate pair); chain grows
// only by 1 DPP + selects (~12 cy). 2048 waves = 2 waves/SIMD.
// Memory structure: R5's proven-best skeleton (CH=8, cur/nxt; R6's deeper
// ping-pong regressed).

#define CH 8  // time-chunk for double-buffered X prefetch

typedef float v2f __attribute__((ext_vector_type(2)));

__device__ __forceinline__ v2f pk_fma(v2f a, v2f b, v2f c) {
    return __builtin_elementwise_fma(a, b, c);
}

// DPP quad_perm lane xor within aligned quads: xor1=0xB1, xor2=0x4E, xor3=0x1B
// row_ror:8 = 0x128: lane L <-> L^8 within each 16-lane row (full rate, no LDS)
template <int CTRL>
__device__ __forceinline__ float dpp_mov(float v) {
    int i = __float_as_int(v);
    int r = __builtin_amdgcn_mov_dpp(i, CTRL, 0xF, 0xF, true);
    return __int_as_float(r);
}

__global__ __launch_bounds__(256) void lstm_h4_kernel(
    const float* __restrict__ X,
    const float* __restrict__ W_ih,
    const float* __restrict__ W_hh,
    const float* __restrict__ b_ih,
    const float* __restrict__ b_hh,
    const float* __restrict__ W_fc,
    const float* __restrict__ b_fc,
    float* __restrict__ out,
    int B, int T)
{
    int gid = blockIdx.x * blockDim.x + threadIdx.x;
    int j  = gid & 3;                               // hidden unit index
    int ps = (gid >> 3) & 1;                        // 0:(f,i) pair 1:(g,o) pair
    int b  = ((gid >> 4) << 1) | ((gid >> 2) & 1);  // sequence index
    if (b >= B) return;

    // Gate order (PyTorch rows): 0-3=i, 4-7=f, 8-11=g, 12-15=o.
    // ps=0 lane: pair (f_j, i_j) rows (4+j, j)
    // ps=1 lane: pair (g_j, o_j) rows (8+j, 12+j)
    // exp2 pre-scales folded: sigmoid rows * MS, tanh (g) row * MT.
    const float MS = -1.44269504f;   // -log2(e)
    const float MT = -2.88539008f;   // -2*log2(e)

    int rA = ps ? (8 + j) : (4 + j);
    int rB = ps ? (12 + j) : j;
    float mA = ps ? MT : MS;

    v2f wih[4], whh[4], bias;
#pragma unroll
    for (int k = 0; k < 4; ++k) {
        wih[k] = (v2f){mA * W_ih[rA * 4 + k], MS * W_ih[rB * 4 + k]};
        int kc = j ^ k;   // h slot k carries h_{j^k} (quad xor broadcast)
        whh[k] = (v2f){mA * W_hh[rA * 4 + kc], MS * W_hh[rB * 4 + kc]};
    }
    bias = (v2f){mA * (b_ih[rA] + b_hh[rA]), MS * (b_ih[rB] + b_hh[rB])};

    const float4* __restrict__ xp = (const float4*)X + (size_t)b * T;

    float h = 0.0f;
    float s = 0.0f;   // scaled cell state: s = -2.8854 * c

    float4 cur[CH], nxt[CH];
#pragma unroll
    for (int i = 0; i < CH; ++i) cur[i] = xp[i];

    for (int tc = 0; tc < T; tc += CH) {
        if (tc + CH < T) {
#pragma unroll
            for (int i = 0; i < CH; ++i) nxt[i] = xp[tc + CH + i];
        }
#pragma unroll
        for (int i = 0; i < CH; ++i) {
            float4 x = cur[i];
            // ---- x path (own gate pair only) ----
            v2f p = bias;
            p = pk_fma(wih[0], (v2f){x.x, x.x}, p);
            p = pk_fma(wih[1], (v2f){x.y, x.y}, p);
            p = pk_fma(wih[2], (v2f){x.z, x.z}, p);
            p = pk_fma(wih[3], (v2f){x.w, x.w}, p);

            // ---- recurrence path (own gate pair only) ----
            float h1 = dpp_mov<0xB1>(h);
            float h2 = dpp_mov<0x4E>(h);
            float h3 = dpp_mov<0x1B>(h);
            p = pk_fma(whh[0], (v2f){h,  h},  p);
            p = pk_fma(whh[1], (v2f){h1, h1}, p);
            p = pk_fma(whh[2], (v2f){h2, h2}, p);
            p = pk_fma(whh[3], (v2f){h3, h3}, p);

            // ---- own-pair e-terms: 2 exp2 per lane (was 4) ----
            float e0 = __builtin_amdgcn_exp2f(p.x);   // ps0: ef  ps1: eg
            float e1 = __builtin_amdgcn_exp2f(p.y);   // ps0: ei  ps1: eo

            // ---- cross-half exchange: DPP row_ror:8 (no LDS!) ----
            float o0 = dpp_mov<0x128>(e0);
            float o1 = dpp_mov<0x128>(e1);
            float ef = ps ? o0 : e0;
            float ei = ps ? o1 : e1;
            float eg = ps ? e0 : o0;
            float eo = ps ? e1 : o1;

            // ---- merged cell update (R5): one rcp for f, i, g ----
            v2f P0 = (v2f){ef, ei} + (v2f){1.0f, 1.0f};  // (pf, pi)
            v2f P1 = (v2f){eg, eo} + (v2f){1.0f, 1.0f};  // (pg, po)
            float qg  = fmaf(2.88539008f, eg, -2.88539008f);
            float pig = P0.y * P1.x;
            float t1  = P0.x * qg;
            float NUM = fmaf(s, pig, t1);
            float DEN = P0.x * pig;
            float rD  = __builtin_amdgcn_rcpf(DEN);
            s = fminf(NUM * rD, 88.0f);   // upper guard; lower side flushes

            // ---- merged output (R5): one rcp for o and tanh(c) ----
            float es = __builtin_amdgcn_exp2f(s);
            float ps_ = 1.0f + es;
            float NH = 1.0f - es;
            float DH = P1.y * ps_;
            float rH = __builtin_amdgcn_rcpf(DH);
            h = NH * rH;
        }
#pragma unroll
        for (int i = 0; i < CH; ++i) cur[i] = nxt[i];
    }

    // out[b] = sum_j h_j * W_fc[j] + b_fc (quad reduce; both halves hold
    // identical h, the j==0 lane of the ps==0 half writes)
    float partial = h * W_fc[j];
    partial += dpp_mov<0xB1>(partial);
    partial += dpp_mov<0x4E>(partial);
    if ((gid & 0xB) == 0) out[b] = partial + b_fc[0];
}

extern "C" void kernel_launch(void* const* d_in, const int* in_sizes, int n_in,
                              void* d_out, int out_size, void* d_ws, size_t ws_size,
                              hipStream_t stream) {
    const float* X    = (const float*)d_in[0];
    const float* W_ih = (const float*)d_in[1];
    const float* W_hh = (const float*)d_in[2];
    const float* b_ih = (const float*)d_in[3];
    const float* b_hh = (const float*)d_in[4];
    const float* W_fc = (const float*)d_in[5];
    const float* b_fc = (const float*)d_in[6];
    float* out = (float*)d_out;

    int B = out_size;                       // 16384
    int T = in_sizes[0] / (B * 4);          // 512 (I=4)

    int threads = B * 8;                    // 8 lanes per sequence
    dim3 block(256);
    dim3 grid((threads + 255) / 256);
    lstm_h4_kernel<<<grid, block, 0, stream>>>(X, W_ih, W_hh, b_ih, b_hh,
                                               W_fc, b_fc, out, B, T);
}